// Round 4
// baseline (1571.617 us; speedup 1.0000x reference)
//
#include <hip/hip_runtime.h>

namespace {

constexpr int kB = 32;
constexpr int kT = 64;
constexpr int kH = 1024;
constexpr int kE = 1024;
constexpr int kV = 16000;
constexpr int kG = 4096;  // 4*H

typedef __attribute__((ext_vector_type(8))) short short8v;
typedef __attribute__((ext_vector_type(4))) float f32x4;

__device__ __forceinline__ float sigmoid_f(float x) {
  return 1.0f / (1.0f + __expf(-x));
}
__device__ __forceinline__ unsigned short f2bf(float x) {
  unsigned int u = __builtin_bit_cast(unsigned int, x);
  u = (u + 0x7FFFu + ((u >> 16) & 1u)) >> 16;
  return (unsigned short)u;
}
__device__ __forceinline__ float bf2f(unsigned short h) {
  return __builtin_bit_cast(float, (unsigned int)h << 16);
}

// ---------------- t=0 logits slice ----------------
__global__ void zero_t0_kernel(float* __restrict__ out) {
  int idx = blockIdx.x * blockDim.x + threadIdx.x;
  if (idx >= kB * kV) return;
  int b = idx / kV, v = idx % kV;
  out[(size_t)b * kT * kV + v] = 0.0f;
}

// JAX outer-index semantics: out[b, 0, output_ids[j, 0]] = 1 for ALL (b, j)
__global__ void ones_t0_kernel(const int* __restrict__ output_ids,
                               float* __restrict__ out) {
  int b = threadIdx.x >> 5;
  int j = threadIdx.x & 31;
  int id = output_ids[j * kT];
  out[(size_t)b * kT * kV + id] = 1.0f;
}

// ---- convert fp32 row-major (R,1024) -> bf16 MFMA B-frag order, 16-row tiles.
// (used by proj_mfma / out_gemm_mfma B operands)
// chunk idx -> lane=idx&63, s=(idx>>6)&31, rg=idx>>11;
// value[e] = W[rg*16 + (lane&15)][s*32 + (lane>>4)*8 + e]
__global__ __launch_bounds__(256)
void convert_frag(const float* __restrict__ src, unsigned short* __restrict__ dst,
                  int nchunks) {
  const int idx = blockIdx.x * 256 + threadIdx.x;
  if (idx >= nchunks) return;
  const int lane = idx & 63;
  const int s = (idx >> 6) & 31;
  const int rg = idx >> 11;
  const int row = rg * 16 + (lane & 15);
  const int k = s * 32 + ((lane >> 4) << 3);
  const float4* p = reinterpret_cast<const float4*>(src + (size_t)row * kH + k);
  float4 v0 = p[0], v1 = p[1];
  short8v o;
  o[0] = (short)f2bf(v0.x); o[1] = (short)f2bf(v0.y);
  o[2] = (short)f2bf(v0.z); o[3] = (short)f2bf(v0.w);
  o[4] = (short)f2bf(v1.x); o[5] = (short)f2bf(v1.y);
  o[6] = (short)f2bf(v1.z); o[7] = (short)f2bf(v1.w);
  *reinterpret_cast<short8v*>(dst + (size_t)idx * 8) = o;
}

// ---- convert fp32 gate-matrix (4096,1024) -> cell B-frag order.
// n-packing: 16 cols = 4 gates x 4 units. chunk idx:
//   l=idx&63, kstep=(idx>>6)&31, uq=(idx>>11)&1, ub=idx>>12 (0..127)
//   n=l&15: g=n>>2, uu=n&3; row = g*1024 + ub*8 + uq*4 + uu
//   k = kstep*32 + (l>>4)*8
__global__ __launch_bounds__(256)
void convert_cell(const float* __restrict__ src, unsigned short* __restrict__ dst,
                  int nchunks) {
  const int idx = blockIdx.x * 256 + threadIdx.x;
  if (idx >= nchunks) return;
  const int l = idx & 63;
  const int kstep = (idx >> 6) & 31;
  const int uq = (idx >> 11) & 1;
  const int ub = idx >> 12;
  const int n = l & 15;
  const int row = (n >> 2) * kH + ub * 8 + uq * 4 + (n & 3);
  const int k = kstep * 32 + ((l >> 4) << 3);
  const float4* p = reinterpret_cast<const float4*>(src + (size_t)row * kH + k);
  float4 v0 = p[0], v1 = p[1];
  short8v o;
  o[0] = (short)f2bf(v0.x); o[1] = (short)f2bf(v0.y);
  o[2] = (short)f2bf(v0.z); o[3] = (short)f2bf(v0.w);
  o[4] = (short)f2bf(v1.x); o[5] = (short)f2bf(v1.y);
  o[6] = (short)f2bf(v1.z); o[7] = (short)f2bf(v1.w);
  *reinterpret_cast<short8v*>(dst + (size_t)idx * 8) = o;
}

// ---- gather embedding rows into A-frag bf16 layout.
__global__ __launch_bounds__(256)
void gather_frag(const float* __restrict__ emb, const int* __restrict__ ids,
                 unsigned short* __restrict__ dst, int ntiles) {
  const int idx = blockIdx.x * 256 + threadIdx.x;
  const int lane = idx & 63;
  const int s = (idx >> 6) & 31;
  const int tile = idx >> 11;
  if (tile >= ntiles) return;
  const int m = tile * 16 + (lane & 15);
  const int t = m >> 5, b = m & 31;
  const int id = ids[b * kT + t];
  const int k = s * 32 + ((lane >> 4) << 3);
  const float4* p = reinterpret_cast<const float4*>(emb + (size_t)id * kE + k);
  float4 v0 = p[0], v1 = p[1];
  short8v o;
  o[0] = (short)f2bf(v0.x); o[1] = (short)f2bf(v0.y);
  o[2] = (short)f2bf(v0.z); o[3] = (short)f2bf(v0.w);
  o[4] = (short)f2bf(v1.x); o[5] = (short)f2bf(v1.y);
  o[6] = (short)f2bf(v1.z); o[7] = (short)f2bf(v1.w);
  *reinterpret_cast<short8v*>(dst + (size_t)idx * 8) = o;
}

// ---- proj MFMA: xproj_bf16[m][4096] = xin . W^T + b0 + b1
__global__ __launch_bounds__(256)
void proj_mfma(const unsigned short* __restrict__ Af,
               const unsigned short* __restrict__ Bf,
               const float* __restrict__ b0, const float* __restrict__ b1,
               unsigned short* __restrict__ dst, int nmt) {
  const int w = threadIdx.x >> 6, lane = threadIdx.x & 63;
  const int mg = blockIdx.x, ng = blockIdx.y;
  f32x4 acc[4][2] = {};
  const unsigned short* Ab[4];
  const unsigned short* Bb[2];
#pragma unroll
  for (int i = 0; i < 4; ++i) {
    int tile = mg * 4 + i;
    if (tile > nmt - 1) tile = nmt - 1;
    Ab[i] = Af + (size_t)tile * 16384 + lane * 8;
  }
#pragma unroll
  for (int j = 0; j < 2; ++j) {
    const int nt = ng * 8 + w * 2 + j;
    Bb[j] = Bf + (size_t)nt * 16384 + lane * 8;
  }
#pragma unroll 2
  for (int s = 0; s < 32; ++s) {
    short8v a[4], b[2];
#pragma unroll
    for (int i = 0; i < 4; ++i) a[i] = *reinterpret_cast<const short8v*>(Ab[i] + s * 512);
#pragma unroll
    for (int j = 0; j < 2; ++j) b[j] = *reinterpret_cast<const short8v*>(Bb[j] + s * 512);
#pragma unroll
    for (int i = 0; i < 4; ++i)
#pragma unroll
      for (int j = 0; j < 2; ++j)
        acc[i][j] = __builtin_amdgcn_mfma_f32_16x16x32_bf16(a[i], b[j], acc[i][j], 0, 0, 0);
  }
#pragma unroll
  for (int i = 0; i < 4; ++i) {
    const int tile = mg * 4 + i;
    if (tile >= nmt) continue;
    const int mbase = tile * 16 + ((lane >> 4) << 2);
#pragma unroll
    for (int j = 0; j < 2; ++j) {
      const int n = (ng * 8 + w * 2 + j) * 16 + (lane & 15);
      const float bj = b0[n] + b1[n];
#pragma unroll
      for (int r = 0; r < 4; ++r) {
        dst[(size_t)(mbase + r) * kG + n] = f2bf(acc[i][j][r] + bj);
      }
    }
  }
}

// ---- output GEMM MFMA: 4x4 tiles per wave. block = 64m x 256n.
__global__ __launch_bounds__(256)
void out_gemm_mfma(const unsigned short* __restrict__ Af,
                   const unsigned short* __restrict__ Bf,
                   const float* __restrict__ bias, float* __restrict__ out) {
  const int w = threadIdx.x >> 6, lane = threadIdx.x & 63;
  const int mg = blockIdx.x, ng = blockIdx.y;
  f32x4 acc[4][4] = {};
  const unsigned short* Ab[4];
  const unsigned short* Bb[4];
#pragma unroll
  for (int i = 0; i < 4; ++i) {
    int tile = mg * 4 + i;
    if (tile > 125) tile = 125;
    Ab[i] = Af + (size_t)tile * 16384 + lane * 8;
  }
#pragma unroll
  for (int j = 0; j < 4; ++j) {
    int nt = ng * 16 + w * 4 + j;
    if (nt > 999) nt = 999;
    Bb[j] = Bf + (size_t)nt * 16384 + lane * 8;
  }
#pragma unroll 2
  for (int s = 0; s < 32; ++s) {
    short8v a[4], b[4];
#pragma unroll
    for (int i = 0; i < 4; ++i) a[i] = *reinterpret_cast<const short8v*>(Ab[i] + s * 512);
#pragma unroll
    for (int j = 0; j < 4; ++j) b[j] = *reinterpret_cast<const short8v*>(Bb[j] + s * 512);
#pragma unroll
    for (int i = 0; i < 4; ++i)
#pragma unroll
      for (int j = 0; j < 4; ++j)
        acc[i][j] = __builtin_amdgcn_mfma_f32_16x16x32_bf16(a[i], b[j], acc[i][j], 0, 0, 0);
  }
#pragma unroll
  for (int i = 0; i < 4; ++i) {
    const int tile = mg * 4 + i;
    if (tile >= 126) continue;
    const int mbase = tile * 16 + ((lane >> 4) << 2);
#pragma unroll
    for (int j = 0; j < 4; ++j) {
      const int n = (ng * 16 + w * 4 + j) * 16 + (lane & 15);
      if (n >= kV) continue;
      const float bj = bias[n];
#pragma unroll
      for (int r = 0; r < 4; ++r) {
        const int m = mbase + r;
        const int sd = m >> 5, bb = m & 31;
        out[(size_t)bb * kT * kV + (size_t)(sd + 1) * kV + n] = acc[i][j][r] + bj;
      }
    }
  }
}

// ---- fused MFMA LSTM cell(s), 256-block version.
// Per job: 128 blocks x 8 units. 16 waves = uq(2) x kq(8); wave computes both
// m-tiles for its (4g x 4u) n-tile over K=128 (ksteps kq*4..+4).
// A (h frags) staged in LDS one input at a time; B streamed from global
// exactly once chip-wide. 8-way K reduction + epilogue in LDS.
struct Job {
  const unsigned short* A0;     // x-input frags (L1) or null
  const unsigned short* W0;     // cell-layout weights for A0
  const unsigned short* A1;     // h-input frags
  const unsigned short* W1;
  const unsigned short* xproj;  // bf16 [32][4096] addend (L0) or null
  const float* bih;             // L1 addends
  const float* bhh;
  float* c;                     // fp32 [32][1024]
  unsigned short* h_swz;        // bf16 A-frag layout out
  unsigned short* h_top;        // bf16 A-frag copy or null
};
struct CellPair { Job j[2]; };

__global__ __launch_bounds__(1024)
void lstm_cells(CellPair P) {
  const Job J = (blockIdx.x >= 128) ? P.j[1] : P.j[0];
  const int ub = blockIdx.x & 127;
  const int tid = threadIdx.x;
  const int wave = tid >> 6, lane = tid & 63;
  const int kq = wave & 7, uq = wave >> 3;

  __shared__ alignas(16) unsigned short As[32768];      // 64 KB: one A input
  __shared__ alignas(16) float Ls[16][2][64][4];        // 32 KB reduce scratch

  const unsigned short* Aps[2];
  const unsigned short* Wps[2];
  int nph;
  if (J.A0) {
    Aps[0] = J.A0; Wps[0] = J.W0; Aps[1] = J.A1; Wps[1] = J.W1; nph = 2;
  } else {
    Aps[0] = J.A1; Wps[0] = J.W1; nph = 1;
  }

  f32x4 acc0 = {0.f, 0.f, 0.f, 0.f};
  f32x4 acc1 = {0.f, 0.f, 0.f, 0.f};

#pragma unroll 1
  for (int ph = 0; ph < nph; ++ph) {
    // stage 64 KB of A frags into LDS (linear copy, frag order)
    const int4* s4 = reinterpret_cast<const int4*>(Aps[ph]);
    int4* d4 = reinterpret_cast<int4*>(&As[0]);
#pragma unroll
    for (int i = 0; i < 4; ++i) d4[i * 1024 + tid] = s4[i * 1024 + tid];
    __syncthreads();
    const unsigned short* Wp = Wps[ph];
#pragma unroll
    for (int s = 0; s < 4; ++s) {
      const int ks = kq * 4 + s;
      short8v a0 = *reinterpret_cast<const short8v*>(&As[(size_t)(ks * 64 + lane) * 8]);
      short8v a1 = *reinterpret_cast<const short8v*>(&As[(size_t)((32 + ks) * 64 + lane) * 8]);
      short8v bv = *reinterpret_cast<const short8v*>(
          Wp + (size_t)(((ub * 2 + uq) * 32 + ks) * 64 + lane) * 8);
      acc0 = __builtin_amdgcn_mfma_f32_16x16x32_bf16(a0, bv, acc0, 0, 0, 0);
      acc1 = __builtin_amdgcn_mfma_f32_16x16x32_bf16(a1, bv, acc1, 0, 0, 0);
    }
    __syncthreads();  // As reusable for next input
  }

  *reinterpret_cast<f32x4*>(&Ls[wave][0][lane][0]) = acc0;
  *reinterpret_cast<f32x4*>(&Ls[wave][1][lane][0]) = acc1;
  __syncthreads();

  if (tid < 256) {
    const int m = tid >> 3;    // 0..31
    const int u8 = tid & 7;    // unit within block
    const int uq2 = u8 >> 2;
    const int mt2 = m >> 4;
    const int r = m & 3;
    const int lm = (m & 12) << 2;
    const int u = ub * 8 + u8;
    float gate[4];
#pragma unroll
    for (int g = 0; g < 4; ++g) {
      const int ln = (g * 4 + (u8 & 3)) | lm;
      const int wb = uq2 << 3;
      float v = 0.f;
#pragma unroll
      for (int q = 0; q < 8; ++q) v += Ls[wb + q][mt2][ln][r];
      if (J.xproj) {
        v += bf2f(J.xproj[m * kG + g * kH + u]);
      } else {
        v += J.bih[g * kH + u] + J.bhh[g * kH + u];
      }
      gate[g] = v;
    }
    const float cold = J.c[m * kH + u];
    const float iv = sigmoid_f(gate[0]);
    const float fv = sigmoid_f(gate[1]);
    const float gv = tanhf(gate[2]);
    const float ov = sigmoid_f(gate[3]);
    const float cnew = fv * cold + iv * gv;
    const float hnew = ov * tanhf(cnew);
    J.c[m * kH + u] = cnew;
    const int ks = u >> 5;
    const int lane3 = (m & 15) | (((u >> 3) & 3) << 4);
    const int e = u & 7;
    const size_t fidx = (size_t)((mt2 * 32 + ks) * 64 + lane3) * 8 + e;
    const unsigned short hb = f2bf(hnew);
    J.h_swz[fidx] = hb;
    if (J.h_top) J.h_top[fidx] = hb;
  }
}

}  // namespace

extern "C" void kernel_launch(void* const* d_in, const int* in_sizes, int n_in,
                              void* d_out, int out_size, void* d_ws, size_t ws_size,
                              hipStream_t stream) {
  const int* input_ids = (const int*)d_in[0];
  const int* output_ids = (const int*)d_in[1];
  const float* enc_emb = (const float*)d_in[2];
  const float* enc_Wih = (const float*)d_in[3];
  const float* enc_Whh = (const float*)d_in[4];
  const float* enc_bih = (const float*)d_in[5];
  const float* enc_bhh = (const float*)d_in[6];
  const float* dec_emb = (const float*)d_in[7];
  const float* dec_Wih = (const float*)d_in[8];
  const float* dec_Whh = (const float*)d_in[9];
  const float* dec_bih = (const float*)d_in[10];
  const float* dec_bhh = (const float*)d_in[11];
  const float* Wout = (const float*)d_in[12];
  const float* bout = (const float*)d_in[13];
  float* out = (float*)d_out;
  char* ws = (char*)d_ws;

  const size_t WL = (size_t)kG * kH;  // per-layer weight stride (elems)

  // ---- workspace layout (bytes) ----
  size_t off = 0;
  // Region dead after encoder; Wout frags alias here (32.77 MB < 37.75 MB)
  unsigned short* wout_frag = (unsigned short*)(ws + 0);
  unsigned short* xproj_enc = (unsigned short*)(ws + off); off += (size_t)kT * kB * kG * 2;
  unsigned short* xin_enc = (unsigned short*)(ws + off); off += (size_t)kT * kB * kH * 2;
  unsigned short* wih0_enc = (unsigned short*)(ws + off); off += WL * 2;
  unsigned short* wih0_dec = (unsigned short*)(ws + off); off += WL * 2;
  // persistent regions
  unsigned short* xproj_dec = (unsigned short*)(ws + off); off += (size_t)(kT - 1) * kB * kG * 2;
  unsigned short* xin_dec = (unsigned short*)(ws + off); off += (size_t)(kT - 1) * kB * kH * 2;
  unsigned short* htop_frag = xin_dec;  // alias: xin_dec dead before decoder starts
  float* c0 = (float*)(ws + off); off += (size_t)kB * kH * 4;
  float* c1 = (float*)(ws + off); off += (size_t)kB * kH * 4;
  unsigned short* h0swz[2];
  unsigned short* h1swz[2];
  h0swz[0] = (unsigned short*)(ws + off); off += (size_t)kB * kH * 2;
  h0swz[1] = (unsigned short*)(ws + off); off += (size_t)kB * kH * 2;
  h1swz[0] = (unsigned short*)(ws + off); off += (size_t)kB * kH * 2;
  h1swz[1] = (unsigned short*)(ws + off); off += (size_t)kB * kH * 2;
  unsigned short* wswz[6];
  for (int i = 0; i < 6; ++i) { wswz[i] = (unsigned short*)(ws + off); off += WL * 2; }

  // zero c0,c1 + h frag buffers (contiguous)
  hipMemsetAsync(c0, 0, (size_t)kB * kH * (4 + 4 + 2 + 2 + 2 + 2), stream);

  // one-time weight conversions
  const int wchunks = kG * (kH / 8);  // 524288
  convert_cell<<<2048, 256, 0, stream>>>(enc_Whh, wswz[0], wchunks);
  convert_cell<<<2048, 256, 0, stream>>>(enc_Wih + WL, wswz[1], wchunks);
  convert_cell<<<2048, 256, 0, stream>>>(enc_Whh + WL, wswz[2], wchunks);
  convert_cell<<<2048, 256, 0, stream>>>(dec_Whh, wswz[3], wchunks);
  convert_cell<<<2048, 256, 0, stream>>>(dec_Wih + WL, wswz[4], wchunks);
  convert_cell<<<2048, 256, 0, stream>>>(dec_Whh + WL, wswz[5], wchunks);
  convert_frag<<<2048, 256, 0, stream>>>(enc_Wih, wih0_enc, wchunks);
  convert_frag<<<2048, 256, 0, stream>>>(dec_Wih, wih0_dec, wchunks);

  // gather embeddings into A-frag layout
  gather_frag<<<128 * 8, 256, 0, stream>>>(enc_emb, input_ids, xin_enc, 128);
  gather_frag<<<126 * 8, 256, 0, stream>>>(dec_emb, output_ids, xin_dec, 126);

  // layer-0 input projections (bias fused, bf16 out)
  proj_mfma<<<dim3(32, 32), 256, 0, stream>>>(xin_enc, wih0_enc, enc_bih, enc_bhh,
                                              xproj_enc, 128);
  proj_mfma<<<dim3(32, 32), 256, 0, stream>>>(xin_dec, wih0_dec, dec_bih, dec_bhh,
                                              xproj_dec, 126);

  // ---- recurrence ----
  auto makeL0 = [&](int t) {
    Job j = {};
    j.A1 = h0swz[t & 1];
    j.W1 = (t < kT) ? wswz[0] : wswz[3];
    j.xproj = (t < kT) ? (xproj_enc + (size_t)t * kB * kG)
                       : (xproj_dec + (size_t)(t - kT) * kB * kG);
    j.c = c0;
    j.h_swz = h0swz[(t + 1) & 1];
    return j;
  };
  auto makeL1 = [&](int t) {
    Job j = {};
    j.A0 = h0swz[(t + 1) & 1];
    j.W0 = (t < kT) ? wswz[1] : wswz[4];
    j.A1 = h1swz[t & 1];
    j.W1 = (t < kT) ? wswz[2] : wswz[5];
    j.bih = ((t < kT) ? enc_bih : dec_bih) + kG;
    j.bhh = ((t < kT) ? enc_bhh : dec_bhh) + kG;
    j.c = c1;
    j.h_swz = h1swz[(t + 1) & 1];
    j.h_top = (t >= kT) ? (htop_frag + (size_t)(t - kT) * kB * kH) : nullptr;
    return j;
  };

  constexpr int kSteps = kT + (kT - 1);  // 127
  {
    CellPair P; P.j[0] = makeL0(0); P.j[1] = P.j[0];
    lstm_cells<<<128, 1024, 0, stream>>>(P);
  }
  for (int p = 1; p <= 63; ++p) {
    CellPair P;
    P.j[0] = makeL1(p - 1);
    P.j[1] = makeL0(p);
    lstm_cells<<<256, 1024, 0, stream>>>(P);
  }
  // xproj_enc fully consumed -> build Wout frags in the aliased region
  convert_frag<<<8000, 256, 0, stream>>>(Wout, wout_frag, kV * (kH / 8));
  for (int p = 64; p <= kSteps - 1; ++p) {
    CellPair P;
    P.j[0] = makeL1(p - 1);
    P.j[1] = makeL0(p);
    lstm_cells<<<256, 1024, 0, stream>>>(P);
  }
  {
    CellPair P; P.j[0] = makeL1(kSteps - 1); P.j[1] = P.j[0];
    lstm_cells<<<128, 1024, 0, stream>>>(P);
  }

  // logits[:, 0, :]
  zero_t0_kernel<<<(kB * kV + 255) / 256, 256, 0, stream>>>(out);
  ones_t0_kernel<<<1, kB * kB, 0, stream>>>(output_ids, out);

  // logits[:, 1:, :]
  out_gemm_mfma<<<dim3(32, 63), 256, 0, stream>>>(htop_frag, wout_frag, bout, out);
}

// Round 5
// 1240.017 us; speedup vs baseline: 1.2674x; 1.2674x over previous
//
#include <hip/hip_runtime.h>

namespace {

constexpr int kB = 32;
constexpr int kT = 64;
constexpr int kH = 1024;
constexpr int kE = 1024;
constexpr int kV = 16000;
constexpr int kG = 4096;  // 4*H

typedef __attribute__((ext_vector_type(8))) short short8v;
typedef __attribute__((ext_vector_type(4))) float f32x4;

__device__ __forceinline__ float sigmoid_f(float x) {
  return 1.0f / (1.0f + __expf(-x));
}
__device__ __forceinline__ unsigned short f2bf(float x) {
  unsigned int u = __builtin_bit_cast(unsigned int, x);
  u = (u + 0x7FFFu + ((u >> 16) & 1u)) >> 16;
  return (unsigned short)u;
}
__device__ __forceinline__ float bf2f(unsigned short h) {
  return __builtin_bit_cast(float, (unsigned int)h << 16);
}

// ---------------- t=0 logits slice ----------------
__global__ void zero_t0_kernel(float* __restrict__ out) {
  int idx = blockIdx.x * blockDim.x + threadIdx.x;
  if (idx >= kB * kV) return;
  int b = idx / kV, v = idx % kV;
  __builtin_nontemporal_store(0.0f, &out[(size_t)b * kT * kV + v]);
}

// JAX outer-index semantics: out[b, 0, output_ids[j, 0]] = 1 for ALL (b, j)
__global__ void ones_t0_kernel(const int* __restrict__ output_ids,
                               float* __restrict__ out) {
  int b = threadIdx.x >> 5;
  int j = threadIdx.x & 31;
  int id = output_ids[j * kT];
  out[(size_t)b * kT * kV + id] = 1.0f;
}

// ---- convert fp32 row-major (R,1024) -> bf16 MFMA B-frag order, 16-row tiles.
__global__ __launch_bounds__(256)
void convert_frag(const float* __restrict__ src, unsigned short* __restrict__ dst,
                  int nchunks) {
  const int idx = blockIdx.x * 256 + threadIdx.x;
  if (idx >= nchunks) return;
  const int lane = idx & 63;
  const int s = (idx >> 6) & 31;
  const int rg = idx >> 11;
  const int row = rg * 16 + (lane & 15);
  const int k = s * 32 + ((lane >> 4) << 3);
  const float4* p = reinterpret_cast<const float4*>(src + (size_t)row * kH + k);
  float4 v0 = p[0], v1 = p[1];
  short8v o;
  o[0] = (short)f2bf(v0.x); o[1] = (short)f2bf(v0.y);
  o[2] = (short)f2bf(v0.z); o[3] = (short)f2bf(v0.w);
  o[4] = (short)f2bf(v1.x); o[5] = (short)f2bf(v1.y);
  o[6] = (short)f2bf(v1.z); o[7] = (short)f2bf(v1.w);
  *reinterpret_cast<short8v*>(dst + (size_t)idx * 8) = o;
}

// ---- convert fp32 gate-matrix (4096,1024) -> cell B-frag order.
// 16 n-cols = 4 gates x 4 units; quad q = ub*2+uq owns units 4q..4q+3.
__global__ __launch_bounds__(256)
void convert_cell(const float* __restrict__ src, unsigned short* __restrict__ dst,
                  int nchunks) {
  const int idx = blockIdx.x * 256 + threadIdx.x;
  if (idx >= nchunks) return;
  const int l = idx & 63;
  const int kstep = (idx >> 6) & 31;
  const int uq = (idx >> 11) & 1;
  const int ub = idx >> 12;
  const int n = l & 15;
  const int row = (n >> 2) * kH + ub * 8 + uq * 4 + (n & 3);
  const int k = kstep * 32 + ((l >> 4) << 3);
  const float4* p = reinterpret_cast<const float4*>(src + (size_t)row * kH + k);
  float4 v0 = p[0], v1 = p[1];
  short8v o;
  o[0] = (short)f2bf(v0.x); o[1] = (short)f2bf(v0.y);
  o[2] = (short)f2bf(v0.z); o[3] = (short)f2bf(v0.w);
  o[4] = (short)f2bf(v1.x); o[5] = (short)f2bf(v1.y);
  o[6] = (short)f2bf(v1.z); o[7] = (short)f2bf(v1.w);
  *reinterpret_cast<short8v*>(dst + (size_t)idx * 8) = o;
}

// ---- gather embedding rows into A-frag bf16 layout.
__global__ __launch_bounds__(256)
void gather_frag(const float* __restrict__ emb, const int* __restrict__ ids,
                 unsigned short* __restrict__ dst, int ntiles) {
  const int idx = blockIdx.x * 256 + threadIdx.x;
  const int lane = idx & 63;
  const int s = (idx >> 6) & 31;
  const int tile = idx >> 11;
  if (tile >= ntiles) return;
  const int m = tile * 16 + (lane & 15);
  const int t = m >> 5, b = m & 31;
  const int id = ids[b * kT + t];
  const int k = s * 32 + ((lane >> 4) << 3);
  const float4* p = reinterpret_cast<const float4*>(emb + (size_t)id * kE + k);
  float4 v0 = p[0], v1 = p[1];
  short8v o;
  o[0] = (short)f2bf(v0.x); o[1] = (short)f2bf(v0.y);
  o[2] = (short)f2bf(v0.z); o[3] = (short)f2bf(v0.w);
  o[4] = (short)f2bf(v1.x); o[5] = (short)f2bf(v1.y);
  o[6] = (short)f2bf(v1.z); o[7] = (short)f2bf(v1.w);
  *reinterpret_cast<short8v*>(dst + (size_t)idx * 8) = o;
}

// ---- proj MFMA: writes xproj in CELL-ORDER: [t][q][m 32][16 = g*4+uu] bf16,
// value = xin . W^T + b0 + b1.
__global__ __launch_bounds__(256)
void proj_mfma(const unsigned short* __restrict__ Af,
               const unsigned short* __restrict__ Bf,
               const float* __restrict__ b0, const float* __restrict__ b1,
               unsigned short* __restrict__ dst, int nmt) {
  const int w = threadIdx.x >> 6, lane = threadIdx.x & 63;
  const int mg = blockIdx.x, ng = blockIdx.y;
  f32x4 acc[4][2] = {};
  const unsigned short* Ab[4];
  const unsigned short* Bb[2];
#pragma unroll
  for (int i = 0; i < 4; ++i) {
    int tile = mg * 4 + i;
    if (tile > nmt - 1) tile = nmt - 1;
    Ab[i] = Af + (size_t)tile * 16384 + lane * 8;
  }
#pragma unroll
  for (int j = 0; j < 2; ++j) {
    const int nt = ng * 8 + w * 2 + j;
    Bb[j] = Bf + (size_t)nt * 16384 + lane * 8;
  }
#pragma unroll 2
  for (int s = 0; s < 32; ++s) {
    short8v a[4], b[2];
#pragma unroll
    for (int i = 0; i < 4; ++i) a[i] = *reinterpret_cast<const short8v*>(Ab[i] + s * 512);
#pragma unroll
    for (int j = 0; j < 2; ++j) b[j] = *reinterpret_cast<const short8v*>(Bb[j] + s * 512);
#pragma unroll
    for (int i = 0; i < 4; ++i)
#pragma unroll
      for (int j = 0; j < 2; ++j)
        acc[i][j] = __builtin_amdgcn_mfma_f32_16x16x32_bf16(a[i], b[j], acc[i][j], 0, 0, 0);
  }
#pragma unroll
  for (int i = 0; i < 4; ++i) {
    const int tile = mg * 4 + i;
    if (tile >= nmt) continue;
    const int mbase = tile * 16 + ((lane >> 4) << 2);
#pragma unroll
    for (int j = 0; j < 2; ++j) {
      const int n = (ng * 8 + w * 2 + j) * 16 + (lane & 15);
      const float bj = b0[n] + b1[n];
      const int g = n >> 10;
      const int u = n & 1023;
      const int q = u >> 2;
      const int uu = u & 3;
#pragma unroll
      for (int r = 0; r < 4; ++r) {
        const int m2 = mbase + r;
        const int t = m2 >> 5, mb = m2 & 31;
        dst[(size_t)t * kB * kG + (size_t)(q * 32 + mb) * 16 + g * 4 + uu] =
            f2bf(acc[i][j][r] + bj);
      }
    }
  }
}

// ---- output GEMM MFMA: 4x4 tiles per wave; nontemporal logits stores.
__global__ __launch_bounds__(256)
void out_gemm_mfma(const unsigned short* __restrict__ Af,
                   const unsigned short* __restrict__ Bf,
                   const float* __restrict__ bias, float* __restrict__ out) {
  const int w = threadIdx.x >> 6, lane = threadIdx.x & 63;
  const int mg = blockIdx.x, ng = blockIdx.y;
  f32x4 acc[4][4] = {};
  const unsigned short* Ab[4];
  const unsigned short* Bb[4];
#pragma unroll
  for (int i = 0; i < 4; ++i) {
    int tile = mg * 4 + i;
    if (tile > 125) tile = 125;
    Ab[i] = Af + (size_t)tile * 16384 + lane * 8;
  }
#pragma unroll
  for (int j = 0; j < 4; ++j) {
    int nt = ng * 16 + w * 4 + j;
    if (nt > 999) nt = 999;
    Bb[j] = Bf + (size_t)nt * 16384 + lane * 8;
  }
#pragma unroll 2
  for (int s = 0; s < 32; ++s) {
    short8v a[4], b[4];
#pragma unroll
    for (int i = 0; i < 4; ++i) a[i] = *reinterpret_cast<const short8v*>(Ab[i] + s * 512);
#pragma unroll
    for (int j = 0; j < 4; ++j) b[j] = *reinterpret_cast<const short8v*>(Bb[j] + s * 512);
#pragma unroll
    for (int i = 0; i < 4; ++i)
#pragma unroll
      for (int j = 0; j < 4; ++j)
        acc[i][j] = __builtin_amdgcn_mfma_f32_16x16x32_bf16(a[i], b[j], acc[i][j], 0, 0, 0);
  }
#pragma unroll
  for (int i = 0; i < 4; ++i) {
    const int tile = mg * 4 + i;
    if (tile >= 126) continue;
    const int mbase = tile * 16 + ((lane >> 4) << 2);
#pragma unroll
    for (int j = 0; j < 4; ++j) {
      const int n = (ng * 16 + w * 4 + j) * 16 + (lane & 15);
      if (n >= kV) continue;
      const float bj = bias[n];
#pragma unroll
      for (int r = 0; r < 4; ++r) {
        const int m = mbase + r;
        const int sd = m >> 5, bb = m & 31;
        __builtin_nontemporal_store(
            acc[i][j][r] + bj,
            &out[(size_t)bb * kT * kV + (size_t)(sd + 1) * kV + n]);
      }
    }
  }
}

// ---- fused pair step: L1(p-1) and L0(p) in ONE block; 256 blocks x 512 thr.
// Block q owns unit-quad q (units 4q..4q+3) of BOTH layers -> reads a fixed
// 96 KB weight slice every launch (L2-pinned). Waves 0-3 stream h0 (shared by
// Wih1 and Whh0); waves 4-7 stream h1 x Whh1. One barrier + 24 KB LDS reduce.
struct CellJob {
  const unsigned short* A0;      // H0[p-1] frags
  const unsigned short* A1;      // H1[p-2] frags
  const unsigned short* Wih1;    // cell layout (quad-indexed)
  const unsigned short* Whh1;
  const unsigned short* Whh0;
  const unsigned short* xprojc;  // cell-order slice for L0(p): [q][32][16]
  const float* bih1;             // layer-1 slice base (pre-offset +kG)
  const float* bhh1;
  float* c0;
  float* c1;
  unsigned short* h0_out;
  unsigned short* h1_out;
  unsigned short* htop_out;      // or null
  int has_l0, has_l1;
};

__global__ __launch_bounds__(512)
void lstm_pair(CellJob J) {
  const int q = blockIdx.x;
  const int tid = threadIdx.x;
  const int wave = tid >> 6;
  const int lane = tid & 63;
  __shared__ alignas(16) float Ls[24][64][4];

  if (wave < 4) {
    f32x4 aI0 = {0.f, 0.f, 0.f, 0.f}, aI1 = {0.f, 0.f, 0.f, 0.f};
    f32x4 aH0 = {0.f, 0.f, 0.f, 0.f}, aH1 = {0.f, 0.f, 0.f, 0.f};
    const int ksb = wave * 8;
#pragma unroll
    for (int s = 0; s < 8; ++s) {
      const int ks = ksb + s;
      const short8v a0 =
          *reinterpret_cast<const short8v*>(J.A0 + (size_t)(ks * 64 + lane) * 8);
      const short8v a1 =
          *reinterpret_cast<const short8v*>(J.A0 + (size_t)((32 + ks) * 64 + lane) * 8);
      const size_t widx = ((size_t)(q * 32 + ks) * 64 + lane) * 8;
      if (J.has_l1) {
        const short8v bi = *reinterpret_cast<const short8v*>(J.Wih1 + widx);
        aI0 = __builtin_amdgcn_mfma_f32_16x16x32_bf16(a0, bi, aI0, 0, 0, 0);
        aI1 = __builtin_amdgcn_mfma_f32_16x16x32_bf16(a1, bi, aI1, 0, 0, 0);
      }
      if (J.has_l0) {
        const short8v bh = *reinterpret_cast<const short8v*>(J.Whh0 + widx);
        aH0 = __builtin_amdgcn_mfma_f32_16x16x32_bf16(a0, bh, aH0, 0, 0, 0);
        aH1 = __builtin_amdgcn_mfma_f32_16x16x32_bf16(a1, bh, aH1, 0, 0, 0);
      }
    }
    *reinterpret_cast<f32x4*>(&Ls[wave * 2 + 0][lane][0]) = aI0;
    *reinterpret_cast<f32x4*>(&Ls[wave * 2 + 1][lane][0]) = aI1;
    *reinterpret_cast<f32x4*>(&Ls[8 + wave * 2 + 0][lane][0]) = aH0;
    *reinterpret_cast<f32x4*>(&Ls[8 + wave * 2 + 1][lane][0]) = aH1;
  } else {
    f32x4 b0 = {0.f, 0.f, 0.f, 0.f}, b1 = {0.f, 0.f, 0.f, 0.f};
    const int ksb = (wave - 4) * 8;
    if (J.has_l1) {
#pragma unroll
      for (int s = 0; s < 8; ++s) {
        const int ks = ksb + s;
        const short8v a0 =
            *reinterpret_cast<const short8v*>(J.A1 + (size_t)(ks * 64 + lane) * 8);
        const short8v a1 =
            *reinterpret_cast<const short8v*>(J.A1 + (size_t)((32 + ks) * 64 + lane) * 8);
        const short8v bh = *reinterpret_cast<const short8v*>(
            J.Whh1 + ((size_t)(q * 32 + ks) * 64 + lane) * 8);
        b0 = __builtin_amdgcn_mfma_f32_16x16x32_bf16(a0, bh, b0, 0, 0, 0);
        b1 = __builtin_amdgcn_mfma_f32_16x16x32_bf16(a1, bh, b1, 0, 0, 0);
      }
    }
    *reinterpret_cast<f32x4*>(&Ls[16 + (wave - 4) * 2 + 0][lane][0]) = b0;
    *reinterpret_cast<f32x4*>(&Ls[16 + (wave - 4) * 2 + 1][lane][0]) = b1;
  }
  __syncthreads();

  if (tid < 128) {
    const int m = tid >> 2;   // batch row 0..31
    const int ul = tid & 3;   // unit within quad
    const int u = q * 4 + ul;
    const int mt = m >> 4, r = m & 3;
    const int lm = (m & 12) << 2;
    const int ksu = u >> 5;
    const int lane3 = (m & 15) | (((u >> 3) & 3) << 4);
    const int e = u & 7;
    const size_t fidx = (size_t)((mt * 32 + ksu) * 64 + lane3) * 8 + e;

    if (J.has_l0) {
      float g0[4];
#pragma unroll
      for (int g = 0; g < 4; ++g) {
        const int ln = (g * 4 + ul) | lm;
        float v = Ls[8 + mt][ln][r] + Ls[10 + mt][ln][r] + Ls[12 + mt][ln][r] +
                  Ls[14 + mt][ln][r];
        v += bf2f(J.xprojc[(q * 32 + m) * 16 + g * 4 + ul]);
        g0[g] = v;
      }
      const float cold = J.c0[m * kH + u];
      const float cnew = sigmoid_f(g0[1]) * cold + sigmoid_f(g0[0]) * tanhf(g0[2]);
      const float hnew = sigmoid_f(g0[3]) * tanhf(cnew);
      J.c0[m * kH + u] = cnew;
      J.h0_out[fidx] = f2bf(hnew);
    }
    if (J.has_l1) {
      float g1[4];
#pragma unroll
      for (int g = 0; g < 4; ++g) {
        const int ln = (g * 4 + ul) | lm;
        float v = Ls[0 + mt][ln][r] + Ls[2 + mt][ln][r] + Ls[4 + mt][ln][r] +
                  Ls[6 + mt][ln][r] + Ls[16 + mt][ln][r] + Ls[18 + mt][ln][r] +
                  Ls[20 + mt][ln][r] + Ls[22 + mt][ln][r];
        v += J.bih1[g * kH + u] + J.bhh1[g * kH + u];
        g1[g] = v;
      }
      const float cold = J.c1[m * kH + u];
      const float cnew = sigmoid_f(g1[1]) * cold + sigmoid_f(g1[0]) * tanhf(g1[2]);
      const float hnew = sigmoid_f(g1[3]) * tanhf(cnew);
      J.c1[m * kH + u] = cnew;
      const unsigned short hb = f2bf(hnew);
      J.h1_out[fidx] = hb;
      if (J.htop_out) J.htop_out[fidx] = hb;
    }
  }
}

}  // namespace

extern "C" void kernel_launch(void* const* d_in, const int* in_sizes, int n_in,
                              void* d_out, int out_size, void* d_ws, size_t ws_size,
                              hipStream_t stream) {
  const int* input_ids = (const int*)d_in[0];
  const int* output_ids = (const int*)d_in[1];
  const float* enc_emb = (const float*)d_in[2];
  const float* enc_Wih = (const float*)d_in[3];
  const float* enc_Whh = (const float*)d_in[4];
  const float* enc_bih = (const float*)d_in[5];
  const float* enc_bhh = (const float*)d_in[6];
  const float* dec_emb = (const float*)d_in[7];
  const float* dec_Wih = (const float*)d_in[8];
  const float* dec_Whh = (const float*)d_in[9];
  const float* dec_bih = (const float*)d_in[10];
  const float* dec_bhh = (const float*)d_in[11];
  const float* Wout = (const float*)d_in[12];
  const float* bout = (const float*)d_in[13];
  float* out = (float*)d_out;
  char* ws = (char*)d_ws;

  const size_t WL = (size_t)kG * kH;  // per-layer weight stride (elems)

  // ---- workspace layout (bytes) ----
  size_t off = 0;
  // Region dead after encoder; Wout frags alias here (32.77 MB < 37.75 MB)
  unsigned short* wout_frag = (unsigned short*)(ws + 0);
  unsigned short* xproj_enc = (unsigned short*)(ws + off); off += (size_t)kT * kB * kG * 2;
  unsigned short* xin_enc = (unsigned short*)(ws + off); off += (size_t)kT * kB * kH * 2;
  unsigned short* wih0_enc = (unsigned short*)(ws + off); off += WL * 2;
  unsigned short* wih0_dec = (unsigned short*)(ws + off); off += WL * 2;
  // persistent regions
  unsigned short* xproj_dec = (unsigned short*)(ws + off); off += (size_t)(kT - 1) * kB * kG * 2;
  unsigned short* xin_dec = (unsigned short*)(ws + off); off += (size_t)(kT - 1) * kB * kH * 2;
  unsigned short* htop_frag = xin_dec;  // alias: xin_dec dead before decoder starts
  float* c0 = (float*)(ws + off); off += (size_t)kB * kH * 4;
  float* c1 = (float*)(ws + off); off += (size_t)kB * kH * 4;
  unsigned short* h0swz[2];
  unsigned short* h1swz[2];
  h0swz[0] = (unsigned short*)(ws + off); off += (size_t)kB * kH * 2;
  h0swz[1] = (unsigned short*)(ws + off); off += (size_t)kB * kH * 2;
  h1swz[0] = (unsigned short*)(ws + off); off += (size_t)kB * kH * 2;
  h1swz[1] = (unsigned short*)(ws + off); off += (size_t)kB * kH * 2;
  unsigned short* wswz[6];
  for (int i = 0; i < 6; ++i) { wswz[i] = (unsigned short*)(ws + off); off += WL * 2; }

  // zero c0,c1 + h frag ping-pong buffers (contiguous)
  hipMemsetAsync(c0, 0, (size_t)kB * kH * (4 + 4 + 2 + 2 + 2 + 2), stream);

  // one-time weight conversions
  const int wchunks = kG * (kH / 8);  // 524288
  convert_cell<<<2048, 256, 0, stream>>>(enc_Whh, wswz[0], wchunks);
  convert_cell<<<2048, 256, 0, stream>>>(enc_Wih + WL, wswz[1], wchunks);
  convert_cell<<<2048, 256, 0, stream>>>(enc_Whh + WL, wswz[2], wchunks);
  convert_cell<<<2048, 256, 0, stream>>>(dec_Whh, wswz[3], wchunks);
  convert_cell<<<2048, 256, 0, stream>>>(dec_Wih + WL, wswz[4], wchunks);
  convert_cell<<<2048, 256, 0, stream>>>(dec_Whh + WL, wswz[5], wchunks);
  convert_frag<<<2048, 256, 0, stream>>>(enc_Wih, wih0_enc, wchunks);
  convert_frag<<<2048, 256, 0, stream>>>(dec_Wih, wih0_dec, wchunks);

  // gather embeddings into A-frag layout
  gather_frag<<<128 * 8, 256, 0, stream>>>(enc_emb, input_ids, xin_enc, 128);
  gather_frag<<<126 * 8, 256, 0, stream>>>(dec_emb, output_ids, xin_dec, 126);

  // layer-0 input projections (bias fused, bf16 cell-order out)
  proj_mfma<<<dim3(32, 32), 256, 0, stream>>>(xin_enc, wih0_enc, enc_bih, enc_bhh,
                                              xproj_enc, 128);
  proj_mfma<<<dim3(32, 32), 256, 0, stream>>>(xin_dec, wih0_dec, dec_bih, dec_bhh,
                                              xproj_dec, 126);

  // ---- recurrence: launch p runs L1(p-1) and L0(p); 128 identical launches.
  for (int p = 0; p <= 127; ++p) {
    CellJob J = {};
    J.has_l0 = (p <= 126);
    J.has_l1 = (p >= 1);
    J.A0 = h0swz[p & 1];          // H0[p-1]
    J.A1 = h1swz[(p + 1) & 1];    // H1[p-2]
    J.c0 = c0;
    J.c1 = c1;
    if (J.has_l0) {
      J.Whh0 = (p < kT) ? wswz[0] : wswz[3];
      J.xprojc = (p < kT) ? (xproj_enc + (size_t)p * kB * kG)
                          : (xproj_dec + (size_t)(p - kT) * kB * kG);
      J.h0_out = h0swz[(p + 1) & 1];
    }
    if (J.has_l1) {
      const bool e1 = (p - 1) < kT;
      J.Wih1 = e1 ? wswz[1] : wswz[4];
      J.Whh1 = e1 ? wswz[2] : wswz[5];
      J.bih1 = (e1 ? enc_bih : dec_bih) + kG;
      J.bhh1 = (e1 ? enc_bhh : dec_bhh) + kG;
      J.h1_out = h1swz[p & 1];
      J.htop_out = (p - 1 >= kT) ? (htop_frag + (size_t)(p - 1 - kT) * kB * kH)
                                 : nullptr;
    }
    lstm_pair<<<256, 512, 0, stream>>>(J);
    if (p == 63) {
      // enc xproj fully consumed -> build Wout frags in the aliased region
      convert_frag<<<8000, 256, 0, stream>>>(Wout, wout_frag, kV * (kH / 8));
    }
  }

  // logits[:, 0, :]
  zero_t0_kernel<<<(kB * kV + 255) / 256, 256, 0, stream>>>(out);
  ones_t0_kernel<<<1, kB * kB, 0, stream>>>(output_ids, out);

  // logits[:, 1:, :]
  out_gemm_mfma<<<dim3(32, 63), 256, 0, stream>>>(htop_frag, wout_frag, bout, out);
}

// Round 7
// 1173.673 us; speedup vs baseline: 1.3391x; 1.0565x over previous
//
#include <hip/hip_runtime.h>

namespace {

constexpr int kB = 32;
constexpr int kT = 64;
constexpr int kH = 1024;
constexpr int kE = 1024;
constexpr int kV = 16000;
constexpr int kG = 4096;  // 4*H

typedef __attribute__((ext_vector_type(8))) short short8v;
typedef __attribute__((ext_vector_type(4))) float f32x4;

__device__ __forceinline__ float sigmoid_f(float x) {
  return 1.0f / (1.0f + __expf(-x));
}
__device__ __forceinline__ unsigned short f2bf(float x) {
  unsigned int u = __builtin_bit_cast(unsigned int, x);
  u = (u + 0x7FFFu + ((u >> 16) & 1u)) >> 16;
  return (unsigned short)u;
}
__device__ __forceinline__ float bf2f(unsigned short h) {
  return __builtin_bit_cast(float, (unsigned int)h << 16);
}

// ---------------- t=0 logits slice ----------------
__global__ void zero_t0_kernel(float* __restrict__ out) {
  int idx = blockIdx.x * blockDim.x + threadIdx.x;
  if (idx >= kB * kV) return;
  int b = idx / kV, v = idx % kV;
  __builtin_nontemporal_store(0.0f, &out[(size_t)b * kT * kV + v]);
}

// JAX outer-index semantics: out[b, 0, output_ids[j, 0]] = 1 for ALL (b, j)
__global__ void ones_t0_kernel(const int* __restrict__ output_ids,
                               float* __restrict__ out) {
  int b = threadIdx.x >> 5;
  int j = threadIdx.x & 31;
  int id = output_ids[j * kT];
  out[(size_t)b * kT * kV + id] = 1.0f;
}

// ---- convert fp32 row-major (R,1024) -> bf16 MFMA B-frag order, 16-row tiles.
__global__ __launch_bounds__(256)
void convert_frag(const float* __restrict__ src, unsigned short* __restrict__ dst,
                  int nchunks) {
  const int idx = blockIdx.x * 256 + threadIdx.x;
  if (idx >= nchunks) return;
  const int lane = idx & 63;
  const int s = (idx >> 6) & 31;
  const int rg = idx >> 11;
  const int row = rg * 16 + (lane & 15);
  const int k = s * 32 + ((lane >> 4) << 3);
  const float4* p = reinterpret_cast<const float4*>(src + (size_t)row * kH + k);
  float4 v0 = p[0], v1 = p[1];
  short8v o;
  o[0] = (short)f2bf(v0.x); o[1] = (short)f2bf(v0.y);
  o[2] = (short)f2bf(v0.z); o[3] = (short)f2bf(v0.w);
  o[4] = (short)f2bf(v1.x); o[5] = (short)f2bf(v1.y);
  o[6] = (short)f2bf(v1.z); o[7] = (short)f2bf(v1.w);
  *reinterpret_cast<short8v*>(dst + (size_t)idx * 8) = o;
}

// ---- convert fp32 gate-matrix (4096,1024) -> cell B-frag order.
// 16 n-cols = 4 gates x 4 units; quad q = ub*2+uq owns units 4q..4q+3.
__global__ __launch_bounds__(256)
void convert_cell(const float* __restrict__ src, unsigned short* __restrict__ dst,
                  int nchunks) {
  const int idx = blockIdx.x * 256 + threadIdx.x;
  if (idx >= nchunks) return;
  const int l = idx & 63;
  const int kstep = (idx >> 6) & 31;
  const int uq = (idx >> 11) & 1;
  const int ub = idx >> 12;
  const int n = l & 15;
  const int row = (n >> 2) * kH + ub * 8 + uq * 4 + (n & 3);
  const int k = kstep * 32 + ((l >> 4) << 3);
  const float4* p = reinterpret_cast<const float4*>(src + (size_t)row * kH + k);
  float4 v0 = p[0], v1 = p[1];
  short8v o;
  o[0] = (short)f2bf(v0.x); o[1] = (short)f2bf(v0.y);
  o[2] = (short)f2bf(v0.z); o[3] = (short)f2bf(v0.w);
  o[4] = (short)f2bf(v1.x); o[5] = (short)f2bf(v1.y);
  o[6] = (short)f2bf(v1.z); o[7] = (short)f2bf(v1.w);
  *reinterpret_cast<short8v*>(dst + (size_t)idx * 8) = o;
}

// ---- gather embedding rows into A-frag bf16 layout.
__global__ __launch_bounds__(256)
void gather_frag(const float* __restrict__ emb, const int* __restrict__ ids,
                 unsigned short* __restrict__ dst, int ntiles) {
  const int idx = blockIdx.x * 256 + threadIdx.x;
  const int lane = idx & 63;
  const int s = (idx >> 6) & 31;
  const int tile = idx >> 11;
  if (tile >= ntiles) return;
  const int m = tile * 16 + (lane & 15);
  const int t = m >> 5, b = m & 31;
  const int id = ids[b * kT + t];
  const int k = s * 32 + ((lane >> 4) << 3);
  const float4* p = reinterpret_cast<const float4*>(emb + (size_t)id * kE + k);
  float4 v0 = p[0], v1 = p[1];
  short8v o;
  o[0] = (short)f2bf(v0.x); o[1] = (short)f2bf(v0.y);
  o[2] = (short)f2bf(v0.z); o[3] = (short)f2bf(v0.w);
  o[4] = (short)f2bf(v1.x); o[5] = (short)f2bf(v1.y);
  o[6] = (short)f2bf(v1.z); o[7] = (short)f2bf(v1.w);
  *reinterpret_cast<short8v*>(dst + (size_t)idx * 8) = o;
}

// ---- proj MFMA: writes xproj in CELL-ORDER: [t][q][m 32][16 = g*4+uu] bf16,
// value = xin . W^T + b0 + b1.
__global__ __launch_bounds__(256)
void proj_mfma(const unsigned short* __restrict__ Af,
               const unsigned short* __restrict__ Bf,
               const float* __restrict__ b0, const float* __restrict__ b1,
               unsigned short* __restrict__ dst, int nmt) {
  const int w = threadIdx.x >> 6, lane = threadIdx.x & 63;
  const int mg = blockIdx.x, ng = blockIdx.y;
  f32x4 acc[4][2] = {};
  const unsigned short* Ab[4];
  const unsigned short* Bb[2];
#pragma unroll
  for (int i = 0; i < 4; ++i) {
    int tile = mg * 4 + i;
    if (tile > nmt - 1) tile = nmt - 1;
    Ab[i] = Af + (size_t)tile * 16384 + lane * 8;
  }
#pragma unroll
  for (int j = 0; j < 2; ++j) {
    const int nt = ng * 8 + w * 2 + j;
    Bb[j] = Bf + (size_t)nt * 16384 + lane * 8;
  }
#pragma unroll 2
  for (int s = 0; s < 32; ++s) {
    short8v a[4], b[2];
#pragma unroll
    for (int i = 0; i < 4; ++i) a[i] = *reinterpret_cast<const short8v*>(Ab[i] + s * 512);
#pragma unroll
    for (int j = 0; j < 2; ++j) b[j] = *reinterpret_cast<const short8v*>(Bb[j] + s * 512);
#pragma unroll
    for (int i = 0; i < 4; ++i)
#pragma unroll
      for (int j = 0; j < 2; ++j)
        acc[i][j] = __builtin_amdgcn_mfma_f32_16x16x32_bf16(a[i], b[j], acc[i][j], 0, 0, 0);
  }
#pragma unroll
  for (int i = 0; i < 4; ++i) {
    const int tile = mg * 4 + i;
    if (tile >= nmt) continue;
    const int mbase = tile * 16 + ((lane >> 4) << 2);
#pragma unroll
    for (int j = 0; j < 2; ++j) {
      const int n = (ng * 8 + w * 2 + j) * 16 + (lane & 15);
      const float bj = b0[n] + b1[n];
      const int g = n >> 10;
      const int u = n & 1023;
      const int q = u >> 2;
      const int uu = u & 3;
#pragma unroll
      for (int r = 0; r < 4; ++r) {
        const int m2 = mbase + r;
        const int t = m2 >> 5, mb = m2 & 31;
        dst[(size_t)t * kB * kG + (size_t)(q * 32 + mb) * 16 + g * 4 + uu] =
            f2bf(acc[i][j][r] + bj);
      }
    }
  }
}

// ---- output GEMM MFMA: 4x4 tiles/wave; LDS-transpose epilogue so logits
// stores are full-line lane-contiguous f32x4 NT stores (no RFO).
__global__ __launch_bounds__(256)
void out_gemm_mfma(const unsigned short* __restrict__ Af,
                   const unsigned short* __restrict__ Bf,
                   const float* __restrict__ bias, float* __restrict__ out) {
  const int w = threadIdx.x >> 6, lane = threadIdx.x & 63;
  const int mg = blockIdx.x, ng = blockIdx.y;
  __shared__ float LsF[64 * 260];
  f32x4 acc[4][4] = {};
  const unsigned short* Ab[4];
  const unsigned short* Bb[4];
#pragma unroll
  for (int i = 0; i < 4; ++i) {
    int tile = mg * 4 + i;
    if (tile > 125) tile = 125;
    Ab[i] = Af + (size_t)tile * 16384 + lane * 8;
  }
#pragma unroll
  for (int j = 0; j < 4; ++j) {
    int nt = ng * 16 + w * 4 + j;
    if (nt > 999) nt = 999;
    Bb[j] = Bf + (size_t)nt * 16384 + lane * 8;
  }
#pragma unroll 2
  for (int s = 0; s < 32; ++s) {
    short8v a[4], b[4];
#pragma unroll
    for (int i = 0; i < 4; ++i) a[i] = *reinterpret_cast<const short8v*>(Ab[i] + s * 512);
#pragma unroll
    for (int j = 0; j < 4; ++j) b[j] = *reinterpret_cast<const short8v*>(Bb[j] + s * 512);
#pragma unroll
    for (int i = 0; i < 4; ++i)
#pragma unroll
      for (int j = 0; j < 4; ++j)
        acc[i][j] = __builtin_amdgcn_mfma_f32_16x16x32_bf16(a[i], b[j], acc[i][j], 0, 0, 0);
  }
  // stage block result (64 rows x 256 cols) in LDS, padded stride 260
#pragma unroll
  for (int i = 0; i < 4; ++i) {
    const int r2b = i * 16 + ((lane >> 4) << 2);
#pragma unroll
    for (int j = 0; j < 4; ++j) {
      const int nloc = (w * 4 + j) * 16 + (lane & 15);
#pragma unroll
      for (int r = 0; r < 4; ++r) LsF[(r2b + r) * 260 + nloc] = acc[i][j][r];
    }
  }
  __syncthreads();
  const int nglob = ng * 256 + lane * 4;
  if (nglob >= kV) return;
  const f32x4 b4 = *reinterpret_cast<const f32x4*>(&bias[nglob]);
#pragma unroll
  for (int it = 0; it < 16; ++it) {
    const int r2 = w * 16 + it;
    const int m = mg * 64 + r2;
    if (m >= 2016) break;
    f32x4 v = *reinterpret_cast<const f32x4*>(&LsF[r2 * 260 + lane * 4]);
    v += b4;
    const int sd = m >> 5, bb = m & 31;
    f32x4* dst = reinterpret_cast<f32x4*>(
        &out[(size_t)bb * kT * kV + (size_t)(sd + 1) * kV + nglob]);
    __builtin_nontemporal_store(v, dst);
  }
}

// ---- fused pair step: L1(p-1) and L0(p) in ONE block; 256 blocks x 512 thr.
// Balanced: every wave handles 4 K-steps of ALL THREE products (Wih1, Whh1,
// Whh0). Block q owns unit-quad q of both layers -> fixed 96 KB weight slice
// every launch (L2-pinned). 8-way LDS reduce + fused nonlinearity epilogue.
struct CellJob {
  const unsigned short* A0;      // H0[p-1] frags
  const unsigned short* A1;      // H1[p-2] frags
  const unsigned short* Wih1;    // cell layout (quad-indexed)
  const unsigned short* Whh1;
  const unsigned short* Whh0;
  const unsigned short* xprojc;  // cell-order slice for L0(p): [q][32][16]
  const float* bih1;             // layer-1 slice base (pre-offset +kG)
  const float* bhh1;
  float* c0;
  float* c1;
  unsigned short* h0_out;
  unsigned short* h1_out;
  unsigned short* htop_out;      // or null
  int has_l0, has_l1;
};

__global__ __launch_bounds__(512)
void lstm_pair(CellJob J) {
  const int q = blockIdx.x;
  const int tid = threadIdx.x;
  const int wave = tid >> 6;
  const int lane = tid & 63;
  // Ls[prod][wave][mt][lane][r]; prod: 0=ih1, 1=hh1, 2=hh0
  __shared__ alignas(16) float Ls[3][8][2][64][4];

  f32x4 aI0 = {0.f, 0.f, 0.f, 0.f}, aI1 = {0.f, 0.f, 0.f, 0.f};
  f32x4 aJ0 = {0.f, 0.f, 0.f, 0.f}, aJ1 = {0.f, 0.f, 0.f, 0.f};
  f32x4 aH0 = {0.f, 0.f, 0.f, 0.f}, aH1 = {0.f, 0.f, 0.f, 0.f};
  const int ksb = wave * 4;
#pragma unroll
  for (int s = 0; s < 4; ++s) {
    const int ks = ksb + s;
    const size_t widx = ((size_t)(q * 32 + ks) * 64 + lane) * 8;
    const short8v a00 =
        *reinterpret_cast<const short8v*>(J.A0 + (size_t)(ks * 64 + lane) * 8);
    const short8v a01 =
        *reinterpret_cast<const short8v*>(J.A0 + (size_t)((32 + ks) * 64 + lane) * 8);
    if (J.has_l1) {
      const short8v bi = *reinterpret_cast<const short8v*>(J.Wih1 + widx);
      aI0 = __builtin_amdgcn_mfma_f32_16x16x32_bf16(a00, bi, aI0, 0, 0, 0);
      aI1 = __builtin_amdgcn_mfma_f32_16x16x32_bf16(a01, bi, aI1, 0, 0, 0);
      const short8v a10 =
          *reinterpret_cast<const short8v*>(J.A1 + (size_t)(ks * 64 + lane) * 8);
      const short8v a11 =
          *reinterpret_cast<const short8v*>(J.A1 + (size_t)((32 + ks) * 64 + lane) * 8);
      const short8v bh1 = *reinterpret_cast<const short8v*>(J.Whh1 + widx);
      aJ0 = __builtin_amdgcn_mfma_f32_16x16x32_bf16(a10, bh1, aJ0, 0, 0, 0);
      aJ1 = __builtin_amdgcn_mfma_f32_16x16x32_bf16(a11, bh1, aJ1, 0, 0, 0);
    }
    if (J.has_l0) {
      const short8v bh0 = *reinterpret_cast<const short8v*>(J.Whh0 + widx);
      aH0 = __builtin_amdgcn_mfma_f32_16x16x32_bf16(a00, bh0, aH0, 0, 0, 0);
      aH1 = __builtin_amdgcn_mfma_f32_16x16x32_bf16(a01, bh0, aH1, 0, 0, 0);
    }
  }
  *reinterpret_cast<f32x4*>(&Ls[0][wave][0][lane][0]) = aI0;
  *reinterpret_cast<f32x4*>(&Ls[0][wave][1][lane][0]) = aI1;
  *reinterpret_cast<f32x4*>(&Ls[1][wave][0][lane][0]) = aJ0;
  *reinterpret_cast<f32x4*>(&Ls[1][wave][1][lane][0]) = aJ1;
  *reinterpret_cast<f32x4*>(&Ls[2][wave][0][lane][0]) = aH0;
  *reinterpret_cast<f32x4*>(&Ls[2][wave][1][lane][0]) = aH1;
  __syncthreads();

  if (tid < 128) {
    const int m = tid >> 2;   // batch row 0..31
    const int ul = tid & 3;   // unit within quad
    const int u = q * 4 + ul;
    const int mt = m >> 4, r = m & 3;
    const int lm = (m & 12) << 2;
    const int ksu = u >> 5;
    const int lane3 = (m & 15) | (((u >> 3) & 3) << 4);
    const int e = u & 7;
    const size_t fidx = (size_t)((mt * 32 + ksu) * 64 + lane3) * 8 + e;

    if (J.has_l0) {
      float g0[4];
#pragma unroll
      for (int g = 0; g < 4; ++g) {
        const int ln = (g * 4 + ul) | lm;
        float v = 0.f;
#pragma unroll
        for (int ww = 0; ww < 8; ++ww) v += Ls[2][ww][mt][ln][r];
        v += bf2f(J.xprojc[(q * 32 + m) * 16 + g * 4 + ul]);
        g0[g] = v;
      }
      const float cold = J.c0[m * kH + u];
      const float cnew = sigmoid_f(g0[1]) * cold + sigmoid_f(g0[0]) * tanhf(g0[2]);
      const float hnew = sigmoid_f(g0[3]) * tanhf(cnew);
      J.c0[m * kH + u] = cnew;
      J.h0_out[fidx] = f2bf(hnew);
    }
    if (J.has_l1) {
      float g1[4];
#pragma unroll
      for (int g = 0; g < 4; ++g) {
        const int ln = (g * 4 + ul) | lm;
        float v = 0.f;
#pragma unroll
        for (int ww = 0; ww < 8; ++ww)
          v += Ls[0][ww][mt][ln][r] + Ls[1][ww][mt][ln][r];
        v += J.bih1[g * kH + u] + J.bhh1[g * kH + u];
        g1[g] = v;
      }
      const float cold = J.c1[m * kH + u];
      const float cnew = sigmoid_f(g1[1]) * cold + sigmoid_f(g1[0]) * tanhf(g1[2]);
      const float hnew = sigmoid_f(g1[3]) * tanhf(cnew);
      J.c1[m * kH + u] = cnew;
      const unsigned short hb = f2bf(hnew);
      J.h1_out[fidx] = hb;
      if (J.htop_out) J.htop_out[fidx] = hb;
    }
  }
}

}  // namespace

extern "C" void kernel_launch(void* const* d_in, const int* in_sizes, int n_in,
                              void* d_out, int out_size, void* d_ws, size_t ws_size,
                              hipStream_t stream) {
  const int* input_ids = (const int*)d_in[0];
  const int* output_ids = (const int*)d_in[1];
  const float* enc_emb = (const float*)d_in[2];
  const float* enc_Wih = (const float*)d_in[3];
  const float* enc_Whh = (const float*)d_in[4];
  const float* enc_bih = (const float*)d_in[5];
  const float* enc_bhh = (const float*)d_in[6];
  const float* dec_emb = (const float*)d_in[7];
  const float* dec_Wih = (const float*)d_in[8];
  const float* dec_Whh = (const float*)d_in[9];
  const float* dec_bih = (const float*)d_in[10];
  const float* dec_bhh = (const float*)d_in[11];
  const float* Wout = (const float*)d_in[12];
  const float* bout = (const float*)d_in[13];
  float* out = (float*)d_out;
  char* ws = (char*)d_ws;

  const size_t WL = (size_t)kG * kH;  // per-layer weight stride (elems)

  // ---- workspace layout (bytes) ----
  size_t off = 0;
  // Region dead after encoder; Wout frags alias here (32.77 MB < 37.75 MB)
  unsigned short* wout_frag = (unsigned short*)(ws + 0);
  unsigned short* xproj_enc = (unsigned short*)(ws + off); off += (size_t)kT * kB * kG * 2;
  unsigned short* xin_enc = (unsigned short*)(ws + off); off += (size_t)kT * kB * kH * 2;
  unsigned short* wih0_enc = (unsigned short*)(ws + off); off += WL * 2;
  unsigned short* wih0_dec = (unsigned short*)(ws + off); off += WL * 2;
  // persistent regions
  unsigned short* xproj_dec = (unsigned short*)(ws + off); off += (size_t)(kT - 1) * kB * kG * 2;
  unsigned short* xin_dec = (unsigned short*)(ws + off); off += (size_t)(kT - 1) * kB * kH * 2;
  unsigned short* htop_frag = xin_dec;  // alias: xin_dec dead before decoder starts
  float* c0 = (float*)(ws + off); off += (size_t)kB * kH * 4;
  float* c1 = (float*)(ws + off); off += (size_t)kB * kH * 4;
  unsigned short* h0swz[2];
  unsigned short* h1swz[2];
  h0swz[0] = (unsigned short*)(ws + off); off += (size_t)kB * kH * 2;
  h0swz[1] = (unsigned short*)(ws + off); off += (size_t)kB * kH * 2;
  h1swz[0] = (unsigned short*)(ws + off); off += (size_t)kB * kH * 2;
  h1swz[1] = (unsigned short*)(ws + off); off += (size_t)kB * kH * 2;
  unsigned short* wswz[6];
  for (int i = 0; i < 6; ++i) { wswz[i] = (unsigned short*)(ws + off); off += WL * 2; }

  // zero c0,c1 + h frag ping-pong buffers (contiguous)
  (void)hipMemsetAsync(c0, 0, (size_t)kB * kH * (4 + 4 + 2 + 2 + 2 + 2), stream);

  // one-time weight conversions
  const int wchunks = kG * (kH / 8);  // 524288
  convert_cell<<<2048, 256, 0, stream>>>(enc_Whh, wswz[0], wchunks);
  convert_cell<<<2048, 256, 0, stream>>>(enc_Wih + WL, wswz[1], wchunks);
  convert_cell<<<2048, 256, 0, stream>>>(enc_Whh + WL, wswz[2], wchunks);
  convert_cell<<<2048, 256, 0, stream>>>(dec_Whh, wswz[3], wchunks);
  convert_cell<<<2048, 256, 0, stream>>>(dec_Wih + WL, wswz[4], wchunks);
  convert_cell<<<2048, 256, 0, stream>>>(dec_Whh + WL, wswz[5], wchunks);
  convert_frag<<<2048, 256, 0, stream>>>(enc_Wih, wih0_enc, wchunks);
  convert_frag<<<2048, 256, 0, stream>>>(dec_Wih, wih0_dec, wchunks);

  // gather embeddings into A-frag layout
  gather_frag<<<128 * 8, 256, 0, stream>>>(enc_emb, input_ids, xin_enc, 128);
  gather_frag<<<126 * 8, 256, 0, stream>>>(dec_emb, output_ids, xin_dec, 126);

  // layer-0 input projections (bias fused, bf16 cell-order out)
  proj_mfma<<<dim3(32, 32), 256, 0, stream>>>(xin_enc, wih0_enc, enc_bih, enc_bhh,
                                              xproj_enc, 128);
  proj_mfma<<<dim3(32, 32), 256, 0, stream>>>(xin_dec, wih0_dec, dec_bih, dec_bhh,
                                              xproj_dec, 126);

  // ---- recurrence: launch p runs L1(p-1) and L0(p); 128 identical launches.
  for (int p = 0; p <= 127; ++p) {
    CellJob J = {};
    J.has_l0 = (p <= 126);
    J.has_l1 = (p >= 1);
    J.A0 = h0swz[p & 1];          // H0[p-1]
    J.A1 = h1swz[(p + 1) & 1];    // H1[p-2]
    J.c0 = c0;
    J.c1 = c1;
    if (J.has_l0) {
      J.Whh0 = (p < kT) ? wswz[0] : wswz[3];
      J.xprojc = (p < kT) ? (xproj_enc + (size_t)p * kB * kG)
                          : (xproj_dec + (size_t)(p - kT) * kB * kG);
      J.h0_out = h0swz[(p + 1) & 1];
    } else {
      J.Whh0 = wswz[3];  // unused but valid
      J.xprojc = xproj_dec;
      J.h0_out = h0swz[(p + 1) & 1];
    }
    if (J.has_l1) {
      const bool e1 = (p - 1) < kT;
      J.Wih1 = e1 ? wswz[1] : wswz[4];
      J.Whh1 = e1 ? wswz[2] : wswz[5];
      J.bih1 = (e1 ? enc_bih : dec_bih) + kG;
      J.bhh1 = (e1 ? enc_bhh : dec_bhh) + kG;
      J.h1_out = h1swz[p & 1];
      J.htop_out = (p - 1 >= kT) ? (htop_frag + (size_t)(p - 1 - kT) * kB * kH)
                                 : nullptr;
    } else {
      J.Wih1 = wswz[1];
      J.Whh1 = wswz[2];
      J.bih1 = enc_bih + kG;
      J.bhh1 = enc_bhh + kG;
      J.h1_out = h1swz[p & 1];
      J.htop_out = nullptr;
    }
    lstm_pair<<<256, 512, 0, stream>>>(J);
    if (p == 63) {
      // enc xproj fully consumed -> build Wout frags in the aliased region
      convert_frag<<<8000, 256, 0, stream>>>(Wout, wout_frag, kV * (kH / 8));
    }
  }

  // logits[:, 0, :]
  zero_t0_kernel<<<(kB * kV + 255) / 256, 256, 0, stream>>>(out);
  ones_t0_kernel<<<1, kB * kB, 0, stream>>>(output_ids, out);

  // logits[:, 1:, :]
  out_gemm_mfma<<<dim3(32, 63), 256, 0, stream>>>(htop_frag, wout_frag, bout, out);
}